// Round 1
// baseline (261.640 us; speedup 1.0000x reference)
//
#include <hip/hip_runtime.h>
#include <hip/hip_bf16.h>

// Problem constants (DBRX MoE): E=8 experts, top-2, H=F=1024, T=2048 tokens.
#define T_TOK 2048
#define HID   1024
#define FF    1024
#define NE    8

using short8   = __attribute__((ext_vector_type(8))) short;
using ushort8v = __attribute__((ext_vector_type(8))) unsigned short;
using f32x4    = __attribute__((ext_vector_type(4))) float;

__device__ __forceinline__ unsigned short f32_to_bf16(float f) {
  union { float f; unsigned int u; } v; v.f = f;
  unsigned int r = v.u + 0x7fffu + ((v.u >> 16) & 1u);
  return (unsigned short)(r >> 16);
}

// ---------------------------------------------------------------- convert
__global__ __launch_bounds__(256) void convert_kernel(const float* __restrict__ src,
                                                      unsigned short* __restrict__ dst,
                                                      int n4) {
  int i = blockIdx.x * 256 + threadIdx.x;
  if (i >= n4) return;
  const float4 v = ((const float4*)src)[i];
  ushort4 o;
  o.x = f32_to_bf16(v.x); o.y = f32_to_bf16(v.y);
  o.z = f32_to_bf16(v.z); o.w = f32_to_bf16(v.w);
  ((ushort4*)dst)[i] = o;
}

// ---------------------------------------------------------------- router
// One wave per token. fp32 logits (exact), softmax, top-2 (ties -> lower index,
// matching jax.lax.top_k), weights = raw softmax probs (DBRX: no renorm).
__global__ __launch_bounds__(256) void router_kernel(const float* __restrict__ x,
                                                     const float* __restrict__ gw,
                                                     int* __restrict__ counts,
                                                     int* __restrict__ toks,
                                                     float* __restrict__ wts) {
  __shared__ float gws[NE * HID];  // 32 KB
  int tid = threadIdx.x;
  for (int i = tid * 4; i < NE * HID; i += 256 * 4)
    *(float4*)&gws[i] = *(const float4*)&gw[i];
  __syncthreads();

  int lane = tid & 63;
  int t = blockIdx.x * 4 + (tid >> 6);

  float acc[NE];
#pragma unroll
  for (int e = 0; e < NE; ++e) acc[e] = 0.f;

  const float* xr = x + (size_t)t * HID;
#pragma unroll
  for (int i = 0; i < HID / 64; ++i) {
    float xv = xr[i * 64 + lane];
#pragma unroll
    for (int e = 0; e < NE; ++e)
      acc[e] = fmaf(xv, gws[e * HID + i * 64 + lane], acc[e]);
  }
#pragma unroll
  for (int off = 32; off >= 1; off >>= 1) {
#pragma unroll
    for (int e = 0; e < NE; ++e) acc[e] += __shfl_xor(acc[e], off);
  }

  if (lane == 0) {
    float m = acc[0];
#pragma unroll
    for (int e = 1; e < NE; ++e) m = fmaxf(m, acc[e]);
    float p[NE], s = 0.f;
#pragma unroll
    for (int e = 0; e < NE; ++e) { p[e] = expf(acc[e] - m); s += p[e]; }
    float inv = 1.f / s;

    int e1 = 0; float b1 = p[0];
#pragma unroll
    for (int e = 1; e < NE; ++e) if (p[e] > b1) { b1 = p[e]; e1 = e; }
    int e2 = -1; float b2 = -1.f;
#pragma unroll
    for (int e = 0; e < NE; ++e) if (e != e1 && p[e] > b2) { b2 = p[e]; e2 = e; }

    int pos1 = atomicAdd(&counts[e1], 1);
    toks[e1 * T_TOK + pos1] = t;  wts[e1 * T_TOK + pos1] = b1 * inv;
    int pos2 = atomicAdd(&counts[e2], 1);
    toks[e2 * T_TOK + pos2] = t;  wts[e2 * T_TOK + pos2] = b2 * inv;
  }
}

// ---------------------------------------------------------------- GEMM1
// Per expert: rows = gathered tokens, computes g (= X W1^T) and v (= X V1^T)
// for one 64-col tile each, fuses hidden = silu(g)*v, writes bf16 hidden.
// Tile: BM=128, BN=64 (per side), BK=64. 256 threads = 4 waves, wave owns 32 rows.
// LDS rows are 128B; XOR-swizzle 16B units by (row&7) to kill bank conflicts.
__global__ __launch_bounds__(256) void gemm1_kernel(const unsigned short* __restrict__ xb,
                                                    const unsigned short* __restrict__ w1b,
                                                    const int* __restrict__ counts,
                                                    const int* __restrict__ toks,
                                                    unsigned short* __restrict__ hidden) {
  int e = blockIdx.z;
  int cnt = counts[e];
  int m0 = blockIdx.y * 128;
  if (m0 >= cnt) return;
  int n0 = blockIdx.x * 64;
  const unsigned short* W = w1b + (size_t)e * (2 * FF * HID);

  __shared__ unsigned short sA[128 * 64];   // 16 KB
  __shared__ unsigned short sBg[64 * 64];   // 8 KB
  __shared__ unsigned short sBv[64 * 64];   // 8 KB

  int tid = threadIdx.x;
  int lane = tid & 63, wid = tid >> 6;

  // staging assignments (hoisted): A = 4 units/thread, Bg/Bv = 2 units/thread
  const unsigned short* aptr[4]; int adst[4];
#pragma unroll
  for (int j = 0; j < 4; ++j) {
    int q = tid + 256 * j;            // 0..1023 : 128 rows x 8 units
    int row = q >> 3, u = q & 7;
    int gr = m0 + row;
    int tok = (gr < cnt) ? toks[e * T_TOK + gr] : 0;
    int su = u ^ (row & 7);           // pre-swizzled source unit
    aptr[j] = xb + (size_t)tok * HID + su * 8;
    adst[j] = row * 64 + u * 8;
  }
  const unsigned short* bgptr[2]; const unsigned short* bvptr[2]; int bdst[2];
#pragma unroll
  for (int j = 0; j < 2; ++j) {
    int q = tid + 256 * j;            // 0..511 : 64 rows x 8 units
    int row = q >> 3, u = q & 7;
    int su = u ^ (row & 7);
    bgptr[j] = W + (size_t)(n0 + row) * HID + su * 8;
    bvptr[j] = W + (size_t)(FF + n0 + row) * HID + su * 8;
    bdst[j] = row * 64 + u * 8;
  }

  f32x4 accg[2][4], accv[2][4];
#pragma unroll
  for (int m = 0; m < 2; ++m)
#pragma unroll
    for (int n = 0; n < 4; ++n) {
      accg[m][n] = (f32x4){0.f, 0.f, 0.f, 0.f};
      accv[m][n] = (f32x4){0.f, 0.f, 0.f, 0.f};
    }

  for (int k0 = 0; k0 < HID; k0 += 64) {
#pragma unroll
    for (int j = 0; j < 4; ++j)
      *(ushort8v*)&sA[adst[j]] = *(const ushort8v*)(aptr[j] + k0);
#pragma unroll
    for (int j = 0; j < 2; ++j) {
      *(ushort8v*)&sBg[bdst[j]] = *(const ushort8v*)(bgptr[j] + k0);
      *(ushort8v*)&sBv[bdst[j]] = *(const ushort8v*)(bvptr[j] + k0);
    }
    __syncthreads();
#pragma unroll
    for (int kk = 0; kk < 2; ++kk) {
      short8 af[2], bgf[4], bvf[4];
#pragma unroll
      for (int m = 0; m < 2; ++m) {
        int row = wid * 32 + m * 16 + (lane & 15);
        int u = (kk * 4 + (lane >> 4)) ^ (row & 7);
        af[m] = *(const short8*)&sA[row * 64 + u * 8];
      }
#pragma unroll
      for (int n = 0; n < 4; ++n) {
        int row = n * 16 + (lane & 15);
        int u = (kk * 4 + (lane >> 4)) ^ (row & 7);
        bgf[n] = *(const short8*)&sBg[row * 64 + u * 8];
        bvf[n] = *(const short8*)&sBv[row * 64 + u * 8];
      }
#pragma unroll
      for (int m = 0; m < 2; ++m)
#pragma unroll
        for (int n = 0; n < 4; ++n) {
          accg[m][n] = __builtin_amdgcn_mfma_f32_16x16x32_bf16(af[m], bgf[n], accg[m][n], 0, 0, 0);
          accv[m][n] = __builtin_amdgcn_mfma_f32_16x16x32_bf16(af[m], bvf[n], accv[m][n], 0, 0, 0);
        }
    }
    __syncthreads();
  }

  // epilogue: hidden = silu(g) * v, bf16 store. C/D layout: col=lane&15, row=(lane>>4)*4+j
  unsigned short* Hseg = hidden + (size_t)e * T_TOK * FF;
#pragma unroll
  for (int m = 0; m < 2; ++m) {
#pragma unroll
    for (int j = 0; j < 4; ++j) {
      int row = wid * 32 + m * 16 + (lane >> 4) * 4 + j;
      int gr = m0 + row;
      if (gr < cnt) {
#pragma unroll
        for (int n = 0; n < 4; ++n) {
          int col = n0 + n * 16 + (lane & 15);
          float g = accg[m][n][j];
          float v = accv[m][n][j];
          float val = (g / (1.f + __expf(-g))) * v;
          Hseg[(size_t)gr * FF + col] = f32_to_bf16(val);
        }
      }
    }
  }
}

// ---------------------------------------------------------------- GEMM2
// out[tok,:] += wt * (hidden_row @ w2_e^T). Same tile structure, one side.
__global__ __launch_bounds__(256) void gemm2_kernel(const unsigned short* __restrict__ hidden,
                                                    const unsigned short* __restrict__ w2b,
                                                    const int* __restrict__ counts,
                                                    const int* __restrict__ toks,
                                                    const float* __restrict__ wts,
                                                    float* __restrict__ out) {
  int e = blockIdx.z;
  int cnt = counts[e];
  int m0 = blockIdx.y * 128;
  if (m0 >= cnt) return;
  int n0 = blockIdx.x * 64;
  const unsigned short* A = hidden + (size_t)e * T_TOK * FF;
  const unsigned short* W = w2b + (size_t)e * HID * FF;

  __shared__ unsigned short sA[128 * 64];
  __shared__ unsigned short sB[64 * 64];

  int tid = threadIdx.x;
  int lane = tid & 63, wid = tid >> 6;

  const unsigned short* aptr[4]; int adst[4];
#pragma unroll
  for (int j = 0; j < 4; ++j) {
    int q = tid + 256 * j;
    int row = q >> 3, u = q & 7;
    int su = u ^ (row & 7);
    aptr[j] = A + (size_t)(m0 + row) * FF + su * 8;   // padded rows read poison: masked at write
    adst[j] = row * 64 + u * 8;
  }
  const unsigned short* bptr[2]; int bdst[2];
#pragma unroll
  for (int j = 0; j < 2; ++j) {
    int q = tid + 256 * j;
    int row = q >> 3, u = q & 7;
    int su = u ^ (row & 7);
    bptr[j] = W + (size_t)(n0 + row) * FF + su * 8;
    bdst[j] = row * 64 + u * 8;
  }

  f32x4 acc[2][4];
#pragma unroll
  for (int m = 0; m < 2; ++m)
#pragma unroll
    for (int n = 0; n < 4; ++n) acc[m][n] = (f32x4){0.f, 0.f, 0.f, 0.f};

  for (int k0 = 0; k0 < FF; k0 += 64) {
#pragma unroll
    for (int j = 0; j < 4; ++j)
      *(ushort8v*)&sA[adst[j]] = *(const ushort8v*)(aptr[j] + k0);
#pragma unroll
    for (int j = 0; j < 2; ++j)
      *(ushort8v*)&sB[bdst[j]] = *(const ushort8v*)(bptr[j] + k0);
    __syncthreads();
#pragma unroll
    for (int kk = 0; kk < 2; ++kk) {
      short8 af[2], bf[4];
#pragma unroll
      for (int m = 0; m < 2; ++m) {
        int row = wid * 32 + m * 16 + (lane & 15);
        int u = (kk * 4 + (lane >> 4)) ^ (row & 7);
        af[m] = *(const short8*)&sA[row * 64 + u * 8];
      }
#pragma unroll
      for (int n = 0; n < 4; ++n) {
        int row = n * 16 + (lane & 15);
        int u = (kk * 4 + (lane >> 4)) ^ (row & 7);
        bf[n] = *(const short8*)&sB[row * 64 + u * 8];
      }
#pragma unroll
      for (int m = 0; m < 2; ++m)
#pragma unroll
        for (int n = 0; n < 4; ++n)
          acc[m][n] = __builtin_amdgcn_mfma_f32_16x16x32_bf16(af[m], bf[n], acc[m][n], 0, 0, 0);
    }
    __syncthreads();
  }

  // epilogue: weighted atomic scatter into out (each out element hit by exactly K=2 experts)
#pragma unroll
  for (int m = 0; m < 2; ++m) {
#pragma unroll
    for (int j = 0; j < 4; ++j) {
      int row = wid * 32 + m * 16 + (lane >> 4) * 4 + j;
      int gr = m0 + row;
      if (gr < cnt) {
        int tok = toks[e * T_TOK + gr];
        float wt = wts[e * T_TOK + gr];
#pragma unroll
        for (int n = 0; n < 4; ++n) {
          int col = n0 + n * 16 + (lane & 15);
          atomicAdd(&out[(size_t)tok * HID + col], acc[m][n][j] * wt);
        }
      }
    }
  }
}

// ---------------------------------------------------------------- launch
extern "C" void kernel_launch(void* const* d_in, const int* in_sizes, int n_in,
                              void* d_out, int out_size, void* d_ws, size_t ws_size,
                              hipStream_t stream) {
  const float* x  = (const float*)d_in[0];
  const float* gw = (const float*)d_in[1];
  const float* w1 = (const float*)d_in[2];
  const float* w2 = (const float*)d_in[3];
  float* out = (float*)d_out;

  // workspace layout (bytes):
  //   0      : counts[8]            (zeroed, 1 KB reserved)
  //   1024   : toks[8*2048] int     (64 KB)
  //   66560  : wts[8*2048] float    (64 KB)
  //   132096 : xb   bf16 x          (4 MB)
  //   +      : w1b  bf16 w1_v1      (32 MB)
  //   +      : w2b  bf16 w2         (16 MB)
  //   +      : hidden bf16 [8*2048][1024] (32 MB)   total ~84.1 MB
  char* ws = (char*)d_ws;
  int*   counts = (int*)ws;
  int*   toks   = (int*)(ws + 1024);
  float* wts    = (float*)(ws + 1024 + 65536);
  unsigned short* xb  = (unsigned short*)(ws + 132096);
  unsigned short* w1b = xb + (size_t)T_TOK * HID;
  unsigned short* w2b = w1b + (size_t)NE * 2 * FF * HID;
  unsigned short* hid = w2b + (size_t)NE * HID * FF;

  hipMemsetAsync(counts, 0, 1024, stream);
  hipMemsetAsync(d_out, 0, (size_t)out_size * sizeof(float), stream);

  convert_kernel<<<(T_TOK * HID / 4 + 255) / 256, 256, 0, stream>>>(x, xb, T_TOK * HID / 4);
  convert_kernel<<<(NE * 2 * FF * HID / 4 + 255) / 256, 256, 0, stream>>>(w1, w1b, NE * 2 * FF * HID / 4);
  convert_kernel<<<(NE * HID * FF / 4 + 255) / 256, 256, 0, stream>>>(w2, w2b, NE * HID * FF / 4);

  router_kernel<<<T_TOK / 4, 256, 0, stream>>>(x, gw, counts, toks, wts);

  gemm1_kernel<<<dim3(FF / 64, T_TOK / 128, NE), 256, 0, stream>>>(xb, w1b, counts, toks, hid);
  gemm2_kernel<<<dim3(HID / 64, T_TOK / 128, NE), 256, 0, stream>>>(hid, w2b, counts, toks, wts, out);
}

// Round 2
// 222.188 us; speedup vs baseline: 1.1776x; 1.1776x over previous
//
#include <hip/hip_runtime.h>
#include <hip/hip_bf16.h>

// Problem constants (DBRX MoE): E=8 experts, top-2, H=F=1024, T=2048 tokens.
#define T_TOK 2048
#define HID   1024
#define FF    1024
#define NE    8
#define CNT_STRIDE 64          // counts[e*CNT_STRIDE]: 256B apart -> no cacheline contention
#define RTOK 16                // tokens per router block

using short8   = __attribute__((ext_vector_type(8))) short;
using ushort8v = __attribute__((ext_vector_type(8))) unsigned short;
using f32x4    = __attribute__((ext_vector_type(4))) float;

__device__ __forceinline__ unsigned short f32_to_bf16(float f) {
  union { float f; unsigned int u; } v; v.f = f;
  unsigned int r = v.u + 0x7fffu + ((v.u >> 16) & 1u);
  return (unsigned short)(r >> 16);
}

// ---------------------------------------------------------------- convert
__global__ __launch_bounds__(256) void convert_kernel(const float* __restrict__ src,
                                                      unsigned short* __restrict__ dst,
                                                      int n4) {
  int i = blockIdx.x * 256 + threadIdx.x;
  if (i >= n4) return;
  const float4 v = ((const float4*)src)[i];
  ushort4 o;
  o.x = f32_to_bf16(v.x); o.y = f32_to_bf16(v.y);
  o.z = f32_to_bf16(v.z); o.w = f32_to_bf16(v.w);
  ((ushort4*)dst)[i] = o;
}

// ---------------------------------------------------------------- router
// 128 blocks x 16 tokens. Wave per token per pass (4 waves x 4 passes).
// fp32 logits (exact), softmax, top-2 (ties -> lower index, matching
// jax.lax.top_k), weights = softmax probs (DBRX: no top-k renorm).
// Block-aggregated expert lists: ONE atomicAdd per expert per block.
__global__ __launch_bounds__(256) void router_kernel(const float* __restrict__ x,
                                                     const float* __restrict__ gw,
                                                     int* __restrict__ counts,
                                                     int* __restrict__ toks,
                                                     float* __restrict__ wts) {
  __shared__ float gws[NE * HID];      // 32 KB
  __shared__ int   s_e[RTOK * 2];
  __shared__ float s_w[RTOK * 2];
  int tid = threadIdx.x;
  for (int i = tid * 4; i < NE * HID; i += 256 * 4)
    *(float4*)&gws[i] = *(const float4*)&gw[i];
  __syncthreads();

  int lane = tid & 63, wid = tid >> 6;
  int t0 = blockIdx.x * RTOK;

#pragma unroll
  for (int pass = 0; pass < RTOK / 4; ++pass) {
    int local = pass * 4 + wid;
    int t = t0 + local;

    float acc[NE];
#pragma unroll
    for (int e = 0; e < NE; ++e) acc[e] = 0.f;

    const float4* xr4 = (const float4*)(x + (size_t)t * HID);
#pragma unroll
    for (int i = 0; i < HID / 256; ++i) {
      float4 xv = xr4[i * 64 + lane];
#pragma unroll
      for (int e = 0; e < NE; ++e) {
        const float4 gv = *(const float4*)&gws[e * HID + (i * 64 + lane) * 4];
        acc[e] = fmaf(xv.x, gv.x, acc[e]);
        acc[e] = fmaf(xv.y, gv.y, acc[e]);
        acc[e] = fmaf(xv.z, gv.z, acc[e]);
        acc[e] = fmaf(xv.w, gv.w, acc[e]);
      }
    }
#pragma unroll
    for (int off = 32; off >= 1; off >>= 1) {
#pragma unroll
      for (int e = 0; e < NE; ++e) acc[e] += __shfl_xor(acc[e], off);
    }

    if (lane == 0) {
      float m = acc[0];
#pragma unroll
      for (int e = 1; e < NE; ++e) m = fmaxf(m, acc[e]);
      float p[NE], s = 0.f;
#pragma unroll
      for (int e = 0; e < NE; ++e) { p[e] = expf(acc[e] - m); s += p[e]; }
      float inv = 1.f / s;

      int e1 = 0; float b1 = p[0];
#pragma unroll
      for (int e = 1; e < NE; ++e) if (p[e] > b1) { b1 = p[e]; e1 = e; }
      int e2 = -1; float b2 = -1.f;
#pragma unroll
      for (int e = 0; e < NE; ++e) if (e != e1 && p[e] > b2) { b2 = p[e]; e2 = e; }

      s_e[local * 2]     = e1;  s_w[local * 2]     = b1 * inv;
      s_e[local * 2 + 1] = e2;  s_w[local * 2 + 1] = b2 * inv;
    }
  }
  __syncthreads();

  // 8 threads, one per expert: count -> one atomicAdd -> direct global writes
  if (tid < NE) {
    int c = 0;
#pragma unroll
    for (int i = 0; i < RTOK * 2; ++i) c += (s_e[i] == tid);
    if (c > 0) {
      int base = atomicAdd(&counts[tid * CNT_STRIDE], c);
      int p = 0;
      for (int i = 0; i < RTOK * 2; ++i) {
        if (s_e[i] == tid) {
          toks[tid * T_TOK + base + p] = t0 + (i >> 1);
          wts[tid * T_TOK + base + p] = s_w[i];
          ++p;
        }
      }
    }
  }
}

// ---------------------------------------------------------------- GEMM1
// Per expert: rows = gathered tokens, computes g (= X W1^T) and v (= X V1^T)
// for one 64-col tile each, fuses hidden = silu(g)*v, writes bf16 hidden.
// Tile: BM=128, BN=64 (per side), BK=64. 256 threads = 4 waves, wave owns 32 rows.
// LDS rows are 128B; XOR-swizzle 16B units by (row&7) to kill bank conflicts.
__global__ __launch_bounds__(256) void gemm1_kernel(const unsigned short* __restrict__ xb,
                                                    const unsigned short* __restrict__ w1b,
                                                    const int* __restrict__ counts,
                                                    const int* __restrict__ toks,
                                                    unsigned short* __restrict__ hidden) {
  int e = blockIdx.z;
  int cnt = counts[e * CNT_STRIDE];
  int m0 = blockIdx.y * 128;
  if (m0 >= cnt) return;
  int n0 = blockIdx.x * 64;
  const unsigned short* W = w1b + (size_t)e * (2 * FF * HID);

  __shared__ unsigned short sA[128 * 64];   // 16 KB
  __shared__ unsigned short sBg[64 * 64];   // 8 KB
  __shared__ unsigned short sBv[64 * 64];   // 8 KB

  int tid = threadIdx.x;
  int lane = tid & 63, wid = tid >> 6;

  const unsigned short* aptr[4]; int adst[4];
#pragma unroll
  for (int j = 0; j < 4; ++j) {
    int q = tid + 256 * j;            // 0..1023 : 128 rows x 8 units
    int row = q >> 3, u = q & 7;
    int gr = m0 + row;
    int tok = (gr < cnt) ? toks[e * T_TOK + gr] : 0;
    int su = u ^ (row & 7);           // pre-swizzled source unit
    aptr[j] = xb + (size_t)tok * HID + su * 8;
    adst[j] = row * 64 + u * 8;
  }
  const unsigned short* bgptr[2]; const unsigned short* bvptr[2]; int bdst[2];
#pragma unroll
  for (int j = 0; j < 2; ++j) {
    int q = tid + 256 * j;            // 0..511 : 64 rows x 8 units
    int row = q >> 3, u = q & 7;
    int su = u ^ (row & 7);
    bgptr[j] = W + (size_t)(n0 + row) * HID + su * 8;
    bvptr[j] = W + (size_t)(FF + n0 + row) * HID + su * 8;
    bdst[j] = row * 64 + u * 8;
  }

  f32x4 accg[2][4], accv[2][4];
#pragma unroll
  for (int m = 0; m < 2; ++m)
#pragma unroll
    for (int n = 0; n < 4; ++n) {
      accg[m][n] = (f32x4){0.f, 0.f, 0.f, 0.f};
      accv[m][n] = (f32x4){0.f, 0.f, 0.f, 0.f};
    }

  for (int k0 = 0; k0 < HID; k0 += 64) {
#pragma unroll
    for (int j = 0; j < 4; ++j)
      *(ushort8v*)&sA[adst[j]] = *(const ushort8v*)(aptr[j] + k0);
#pragma unroll
    for (int j = 0; j < 2; ++j) {
      *(ushort8v*)&sBg[bdst[j]] = *(const ushort8v*)(bgptr[j] + k0);
      *(ushort8v*)&sBv[bdst[j]] = *(const ushort8v*)(bvptr[j] + k0);
    }
    __syncthreads();
#pragma unroll
    for (int kk = 0; kk < 2; ++kk) {
      short8 af[2], bgf[4], bvf[4];
#pragma unroll
      for (int m = 0; m < 2; ++m) {
        int row = wid * 32 + m * 16 + (lane & 15);
        int u = (kk * 4 + (lane >> 4)) ^ (row & 7);
        af[m] = *(const short8*)&sA[row * 64 + u * 8];
      }
#pragma unroll
      for (int n = 0; n < 4; ++n) {
        int row = n * 16 + (lane & 15);
        int u = (kk * 4 + (lane >> 4)) ^ (row & 7);
        bgf[n] = *(const short8*)&sBg[row * 64 + u * 8];
        bvf[n] = *(const short8*)&sBv[row * 64 + u * 8];
      }
#pragma unroll
      for (int m = 0; m < 2; ++m)
#pragma unroll
        for (int n = 0; n < 4; ++n) {
          accg[m][n] = __builtin_amdgcn_mfma_f32_16x16x32_bf16(af[m], bgf[n], accg[m][n], 0, 0, 0);
          accv[m][n] = __builtin_amdgcn_mfma_f32_16x16x32_bf16(af[m], bvf[n], accv[m][n], 0, 0, 0);
        }
    }
    __syncthreads();
  }

  // epilogue: hidden = silu(g) * v, bf16 store. C/D layout: col=lane&15, row=(lane>>4)*4+j
  unsigned short* Hseg = hidden + (size_t)e * T_TOK * FF;
#pragma unroll
  for (int m = 0; m < 2; ++m) {
#pragma unroll
    for (int j = 0; j < 4; ++j) {
      int row = wid * 32 + m * 16 + (lane >> 4) * 4 + j;
      int gr = m0 + row;
      if (gr < cnt) {
#pragma unroll
        for (int n = 0; n < 4; ++n) {
          int col = n0 + n * 16 + (lane & 15);
          float g = accg[m][n][j];
          float v = accv[m][n][j];
          float val = (g / (1.f + __expf(-g))) * v;
          Hseg[(size_t)gr * FF + col] = f32_to_bf16(val);
        }
      }
    }
  }
}

// ---------------------------------------------------------------- GEMM2
// out[tok,:] += wt * (hidden_row @ w2_e^T). Same tile structure, one side.
__global__ __launch_bounds__(256) void gemm2_kernel(const unsigned short* __restrict__ hidden,
                                                    const unsigned short* __restrict__ w2b,
                                                    const int* __restrict__ counts,
                                                    const int* __restrict__ toks,
                                                    const float* __restrict__ wts,
                                                    float* __restrict__ out) {
  int e = blockIdx.z;
  int cnt = counts[e * CNT_STRIDE];
  int m0 = blockIdx.y * 128;
  if (m0 >= cnt) return;
  int n0 = blockIdx.x * 64;
  const unsigned short* A = hidden + (size_t)e * T_TOK * FF;
  const unsigned short* W = w2b + (size_t)e * HID * FF;

  __shared__ unsigned short sA[128 * 64];
  __shared__ unsigned short sB[64 * 64];

  int tid = threadIdx.x;
  int lane = tid & 63, wid = tid >> 6;

  const unsigned short* aptr[4]; int adst[4];
#pragma unroll
  for (int j = 0; j < 4; ++j) {
    int q = tid + 256 * j;
    int row = q >> 3, u = q & 7;
    int su = u ^ (row & 7);
    aptr[j] = A + (size_t)(m0 + row) * FF + su * 8;   // padded rows read stale: masked at write
    adst[j] = row * 64 + u * 8;
  }
  const unsigned short* bptr[2]; int bdst[2];
#pragma unroll
  for (int j = 0; j < 2; ++j) {
    int q = tid + 256 * j;
    int row = q >> 3, u = q & 7;
    int su = u ^ (row & 7);
    bptr[j] = W + (size_t)(n0 + row) * FF + su * 8;
    bdst[j] = row * 64 + u * 8;
  }

  f32x4 acc[2][4];
#pragma unroll
  for (int m = 0; m < 2; ++m)
#pragma unroll
    for (int n = 0; n < 4; ++n) acc[m][n] = (f32x4){0.f, 0.f, 0.f, 0.f};

  for (int k0 = 0; k0 < FF; k0 += 64) {
#pragma unroll
    for (int j = 0; j < 4; ++j)
      *(ushort8v*)&sA[adst[j]] = *(const ushort8v*)(aptr[j] + k0);
#pragma unroll
    for (int j = 0; j < 2; ++j)
      *(ushort8v*)&sB[bdst[j]] = *(const ushort8v*)(bptr[j] + k0);
    __syncthreads();
#pragma unroll
    for (int kk = 0; kk < 2; ++kk) {
      short8 af[2], bf[4];
#pragma unroll
      for (int m = 0; m < 2; ++m) {
        int row = wid * 32 + m * 16 + (lane & 15);
        int u = (kk * 4 + (lane >> 4)) ^ (row & 7);
        af[m] = *(const short8*)&sA[row * 64 + u * 8];
      }
#pragma unroll
      for (int n = 0; n < 4; ++n) {
        int row = n * 16 + (lane & 15);
        int u = (kk * 4 + (lane >> 4)) ^ (row & 7);
        bf[n] = *(const short8*)&sB[row * 64 + u * 8];
      }
#pragma unroll
      for (int m = 0; m < 2; ++m)
#pragma unroll
        for (int n = 0; n < 4; ++n)
          acc[m][n] = __builtin_amdgcn_mfma_f32_16x16x32_bf16(af[m], bf[n], acc[m][n], 0, 0, 0);
    }
    __syncthreads();
  }

  // epilogue: weighted atomic scatter into out (each out element hit by exactly K=2 experts)
#pragma unroll
  for (int m = 0; m < 2; ++m) {
#pragma unroll
    for (int j = 0; j < 4; ++j) {
      int row = wid * 32 + m * 16 + (lane >> 4) * 4 + j;
      int gr = m0 + row;
      if (gr < cnt) {
        int tok = toks[e * T_TOK + gr];
        float wt = wts[e * T_TOK + gr];
#pragma unroll
        for (int n = 0; n < 4; ++n) {
          int col = n0 + n * 16 + (lane & 15);
          atomicAdd(&out[(size_t)tok * HID + col], acc[m][n][j] * wt);
        }
      }
    }
  }
}

// ---------------------------------------------------------------- launch
extern "C" void kernel_launch(void* const* d_in, const int* in_sizes, int n_in,
                              void* d_out, int out_size, void* d_ws, size_t ws_size,
                              hipStream_t stream) {
  const float* x  = (const float*)d_in[0];
  const float* gw = (const float*)d_in[1];
  const float* w1 = (const float*)d_in[2];
  const float* w2 = (const float*)d_in[3];
  float* out = (float*)d_out;

  // workspace layout (bytes):
  //   0      : counts[8 * CNT_STRIDE] int  (2 KB, 4 KB reserved)
  //   4096   : toks[8*2048] int            (64 KB)
  //   69632  : wts[8*2048] float           (64 KB)
  //   135168 : xb   bf16 x                 (4 MB)
  //   +      : w1b  bf16 w1_v1             (32 MB)
  //   +      : w2b  bf16 w2                (16 MB)
  //   +      : hidden bf16 [8*2048][1024]  (32 MB)   total ~84.1 MB
  char* ws = (char*)d_ws;
  int*   counts = (int*)ws;
  int*   toks   = (int*)(ws + 4096);
  float* wts    = (float*)(ws + 4096 + 65536);
  unsigned short* xb  = (unsigned short*)(ws + 135168);
  unsigned short* w1b = xb + (size_t)T_TOK * HID;
  unsigned short* w2b = w1b + (size_t)NE * 2 * FF * HID;
  unsigned short* hid = w2b + (size_t)NE * HID * FF;

  hipMemsetAsync(counts, 0, 4096, stream);
  hipMemsetAsync(d_out, 0, (size_t)out_size * sizeof(float), stream);

  convert_kernel<<<(T_TOK * HID / 4 + 255) / 256, 256, 0, stream>>>(x, xb, T_TOK * HID / 4);
  convert_kernel<<<(NE * 2 * FF * HID / 4 + 255) / 256, 256, 0, stream>>>(w1, w1b, NE * 2 * FF * HID / 4);
  convert_kernel<<<(NE * HID * FF / 4 + 255) / 256, 256, 0, stream>>>(w2, w2b, NE * HID * FF / 4);

  router_kernel<<<T_TOK / RTOK, 256, 0, stream>>>(x, gw, counts, toks, wts);

  gemm1_kernel<<<dim3(FF / 64, T_TOK / 128, NE), 256, 0, stream>>>(xb, w1b, counts, toks, hid);
  gemm2_kernel<<<dim3(HID / 64, T_TOK / 128, NE), 256, 0, stream>>>(hid, w2b, counts, toks, wts, out);
}

// Round 5
// 221.371 us; speedup vs baseline: 1.1819x; 1.0037x over previous
//
#include <hip/hip_runtime.h>
#include <hip/hip_bf16.h>

// Problem constants (DBRX MoE): E=8 experts, top-2, H=F=1024, T=2048 tokens.
#define T_TOK 2048
#define HID   1024
#define FF    1024
#define NE    8
#define CNT_STRIDE 64          // counts[e*CNT_STRIDE]: 256B apart -> no cacheline contention
#define RTOK 16                // tokens per router block

using short8   = __attribute__((ext_vector_type(8))) short;
using ushort8v = __attribute__((ext_vector_type(8))) unsigned short;
using f32x4    = __attribute__((ext_vector_type(4))) float;

__device__ __forceinline__ unsigned short f32_to_bf16(float f) {
  union { float f; unsigned int u; } v; v.f = f;
  unsigned int r = v.u + 0x7fffu + ((v.u >> 16) & 1u);
  return (unsigned short)(r >> 16);
}

// ---------------------------------------------------------------- convert
__global__ __launch_bounds__(256) void convert_kernel(const float* __restrict__ src,
                                                      unsigned short* __restrict__ dst,
                                                      int n4) {
  int i = blockIdx.x * 256 + threadIdx.x;
  if (i >= n4) return;
  const float4 v = ((const float4*)src)[i];
  ushort4 o;
  o.x = f32_to_bf16(v.x); o.y = f32_to_bf16(v.y);
  o.z = f32_to_bf16(v.z); o.w = f32_to_bf16(v.w);
  ((ushort4*)dst)[i] = o;
}

// ---------------------------------------------------------------- router
// 128 blocks x 16 tokens; wave handles 4 tokens. ALL global loads hoisted
// (8 float4 gw + 16 float4 x in flight per lane -> Little's-law BW regime,
// was latency-bound at ~100 GB/s with 4 in flight). fp32 logits (exact
// ordering for top-2), softmax probs as weights (DBRX: no renorm).
// Block-aggregated expert lists: ONE atomicAdd per expert per block.
__global__ __launch_bounds__(256) void router_kernel(const float* __restrict__ x,
                                                     const float* __restrict__ gw,
                                                     int* __restrict__ counts,
                                                     int* __restrict__ toks,
                                                     float* __restrict__ wts) {
  __shared__ float gws[NE * HID];      // 32 KB
  __shared__ int   s_e[RTOK * 2];
  __shared__ float s_w[RTOK * 2];
  int tid = threadIdx.x;
  int lane = tid & 63, wid = tid >> 6;
  int t0 = blockIdx.x * RTOK;

  // 1) issue gw loads (8 float4 / thread)
  float4 greg[8];
#pragma unroll
  for (int j = 0; j < 8; ++j) greg[j] = ((const float4*)gw)[j * 256 + tid];

  // 2) issue x loads (4 tokens / wave, 4 float4 each) — all in flight together
  float4 xv[4][4];
#pragma unroll
  for (int tk = 0; tk < 4; ++tk) {
    const float4* xr4 = (const float4*)(x + (size_t)(t0 + wid * 4 + tk) * HID);
#pragma unroll
    for (int c = 0; c < 4; ++c) xv[tk][c] = xr4[c * 64 + lane];
  }

  // 3) stage gw to LDS
#pragma unroll
  for (int j = 0; j < 8; ++j) ((float4*)&gws[0])[j * 256 + tid] = greg[j];
  __syncthreads();

  // 4) dot products: gw chunk shared across the wave's 4 tokens (32 LDS reads)
  float acc[4][NE];
#pragma unroll
  for (int tk = 0; tk < 4; ++tk)
#pragma unroll
    for (int e = 0; e < NE; ++e) acc[tk][e] = 0.f;

#pragma unroll
  for (int c = 0; c < 4; ++c) {
#pragma unroll
    for (int e = 0; e < NE; ++e) {
      const float4 gv = *(const float4*)&gws[e * HID + (c * 64 + lane) * 4];
#pragma unroll
      for (int tk = 0; tk < 4; ++tk) {
        acc[tk][e] = fmaf(xv[tk][c].x, gv.x, acc[tk][e]);
        acc[tk][e] = fmaf(xv[tk][c].y, gv.y, acc[tk][e]);
        acc[tk][e] = fmaf(xv[tk][c].z, gv.z, acc[tk][e]);
        acc[tk][e] = fmaf(xv[tk][c].w, gv.w, acc[tk][e]);
      }
    }
  }

  // 5) wave reduce + per-token softmax/top-2
#pragma unroll
  for (int tk = 0; tk < 4; ++tk) {
#pragma unroll
    for (int off = 32; off >= 1; off >>= 1) {
#pragma unroll
      for (int e = 0; e < NE; ++e) acc[tk][e] += __shfl_xor(acc[tk][e], off);
    }
    if (lane == 0) {
      int local = wid * 4 + tk;
      float m = acc[tk][0];
#pragma unroll
      for (int e = 1; e < NE; ++e) m = fmaxf(m, acc[tk][e]);
      float p[NE], s = 0.f;
#pragma unroll
      for (int e = 0; e < NE; ++e) { p[e] = __expf(acc[tk][e] - m); s += p[e]; }
      float inv = 1.f / s;

      int e1 = 0; float b1 = p[0];
#pragma unroll
      for (int e = 1; e < NE; ++e) if (p[e] > b1) { b1 = p[e]; e1 = e; }
      int e2 = -1; float b2 = -1.f;
#pragma unroll
      for (int e = 0; e < NE; ++e) if (e != e1 && p[e] > b2) { b2 = p[e]; e2 = e; }

      s_e[local * 2]     = e1;  s_w[local * 2]     = b1 * inv;
      s_e[local * 2 + 1] = e2;  s_w[local * 2 + 1] = b2 * inv;
    }
  }
  __syncthreads();

  // 6) 8 threads, one per expert: count -> one atomicAdd -> direct global writes
  if (tid < NE) {
    int c = 0;
#pragma unroll
    for (int i = 0; i < RTOK * 2; ++i) c += (s_e[i] == tid);
    if (c > 0) {
      int base = atomicAdd(&counts[tid * CNT_STRIDE], c);
      int p = 0;
      for (int i = 0; i < RTOK * 2; ++i) {
        if (s_e[i] == tid) {
          toks[tid * T_TOK + base + p] = t0 + (i >> 1);
          wts[tid * T_TOK + base + p] = s_w[i];
          ++p;
        }
      }
    }
  }
}

// ---------------------------------------------------------------- GEMM1
// Per expert: rows = gathered tokens, computes g (= X W1^T) and v (= X V1^T)
// for one 64-col tile each, fuses hidden = silu(g)*v, writes bf16 hidden.
// Tile: BM=128, BN=64 (per side), BK=64. 256 threads = 4 waves, wave owns 32 rows.
// LDS rows are 128B; XOR-swizzle 16B units by (row&7) to kill bank conflicts.
__global__ __launch_bounds__(256) void gemm1_kernel(const unsigned short* __restrict__ xb,
                                                    const unsigned short* __restrict__ w1b,
                                                    const int* __restrict__ counts,
                                                    const int* __restrict__ toks,
                                                    unsigned short* __restrict__ hidden) {
  int e = blockIdx.z;
  int cnt = counts[e * CNT_STRIDE];
  int m0 = blockIdx.y * 128;
  if (m0 >= cnt) return;
  int n0 = blockIdx.x * 64;
  const unsigned short* W = w1b + (size_t)e * (2 * FF * HID);

  __shared__ unsigned short sA[128 * 64];   // 16 KB
  __shared__ unsigned short sBg[64 * 64];   // 8 KB
  __shared__ unsigned short sBv[64 * 64];   // 8 KB

  int tid = threadIdx.x;
  int lane = tid & 63, wid = tid >> 6;

  const unsigned short* aptr[4]; int adst[4];
#pragma unroll
  for (int j = 0; j < 4; ++j) {
    int q = tid + 256 * j;            // 0..1023 : 128 rows x 8 units
    int row = q >> 3, u = q & 7;
    int gr = m0 + row;
    int tok = (gr < cnt) ? toks[e * T_TOK + gr] : 0;
    int su = u ^ (row & 7);           // pre-swizzled source unit
    aptr[j] = xb + (size_t)tok * HID + su * 8;
    adst[j] = row * 64 + u * 8;
  }
  const unsigned short* bgptr[2]; const unsigned short* bvptr[2]; int bdst[2];
#pragma unroll
  for (int j = 0; j < 2; ++j) {
    int q = tid + 256 * j;            // 0..511 : 64 rows x 8 units
    int row = q >> 3, u = q & 7;
    int su = u ^ (row & 7);
    bgptr[j] = W + (size_t)(n0 + row) * HID + su * 8;
    bvptr[j] = W + (size_t)(FF + n0 + row) * HID + su * 8;
    bdst[j] = row * 64 + u * 8;
  }

  f32x4 accg[2][4], accv[2][4];
#pragma unroll
  for (int m = 0; m < 2; ++m)
#pragma unroll
    for (int n = 0; n < 4; ++n) {
      accg[m][n] = (f32x4){0.f, 0.f, 0.f, 0.f};
      accv[m][n] = (f32x4){0.f, 0.f, 0.f, 0.f};
    }

  for (int k0 = 0; k0 < HID; k0 += 64) {
#pragma unroll
    for (int j = 0; j < 4; ++j)
      *(ushort8v*)&sA[adst[j]] = *(const ushort8v*)(aptr[j] + k0);
#pragma unroll
    for (int j = 0; j < 2; ++j) {
      *(ushort8v*)&sBg[bdst[j]] = *(const ushort8v*)(bgptr[j] + k0);
      *(ushort8v*)&sBv[bdst[j]] = *(const ushort8v*)(bvptr[j] + k0);
    }
    __syncthreads();
#pragma unroll
    for (int kk = 0; kk < 2; ++kk) {
      short8 af[2], bgf[4], bvf[4];
#pragma unroll
      for (int m = 0; m < 2; ++m) {
        int row = wid * 32 + m * 16 + (lane & 15);
        int u = (kk * 4 + (lane >> 4)) ^ (row & 7);
        af[m] = *(const short8*)&sA[row * 64 + u * 8];
      }
#pragma unroll
      for (int n = 0; n < 4; ++n) {
        int row = n * 16 + (lane & 15);
        int u = (kk * 4 + (lane >> 4)) ^ (row & 7);
        bgf[n] = *(const short8*)&sBg[row * 64 + u * 8];
        bvf[n] = *(const short8*)&sBv[row * 64 + u * 8];
      }
#pragma unroll
      for (int m = 0; m < 2; ++m)
#pragma unroll
        for (int n = 0; n < 4; ++n) {
          accg[m][n] = __builtin_amdgcn_mfma_f32_16x16x32_bf16(af[m], bgf[n], accg[m][n], 0, 0, 0);
          accv[m][n] = __builtin_amdgcn_mfma_f32_16x16x32_bf16(af[m], bvf[n], accv[m][n], 0, 0, 0);
        }
    }
    __syncthreads();
  }

  // epilogue: hidden = silu(g) * v, bf16 store. C/D layout: col=lane&15, row=(lane>>4)*4+j
  unsigned short* Hseg = hidden + (size_t)e * T_TOK * FF;
#pragma unroll
  for (int m = 0; m < 2; ++m) {
#pragma unroll
    for (int j = 0; j < 4; ++j) {
      int row = wid * 32 + m * 16 + (lane >> 4) * 4 + j;
      int gr = m0 + row;
      if (gr < cnt) {
#pragma unroll
        for (int n = 0; n < 4; ++n) {
          int col = n0 + n * 16 + (lane & 15);
          float g = accg[m][n][j];
          float v = accv[m][n][j];
          float val = (g / (1.f + __expf(-g))) * v;
          Hseg[(size_t)gr * FF + col] = f32_to_bf16(val);
        }
      }
    }
  }
}

// ---------------------------------------------------------------- GEMM2
// out[tok,:] += wt * (hidden_row @ w2_e^T). Same tile structure, one side.
__global__ __launch_bounds__(256) void gemm2_kernel(const unsigned short* __restrict__ hidden,
                                                    const unsigned short* __restrict__ w2b,
                                                    const int* __restrict__ counts,
                                                    const int* __restrict__ toks,
                                                    const float* __restrict__ wts,
                                                    float* __restrict__ out) {
  int e = blockIdx.z;
  int cnt = counts[e * CNT_STRIDE];
  int m0 = blockIdx.y * 128;
  if (m0 >= cnt) return;
  int n0 = blockIdx.x * 64;
  const unsigned short* A = hidden + (size_t)e * T_TOK * FF;
  const unsigned short* W = w2b + (size_t)e * HID * FF;

  __shared__ unsigned short sA[128 * 64];
  __shared__ unsigned short sB[64 * 64];

  int tid = threadIdx.x;
  int lane = tid & 63, wid = tid >> 6;

  const unsigned short* aptr[4]; int adst[4];
#pragma unroll
  for (int j = 0; j < 4; ++j) {
    int q = tid + 256 * j;
    int row = q >> 3, u = q & 7;
    int su = u ^ (row & 7);
    aptr[j] = A + (size_t)(m0 + row) * FF + su * 8;   // padded rows read stale: masked at write
    adst[j] = row * 64 + u * 8;
  }
  const unsigned short* bptr[2]; int bdst[2];
#pragma unroll
  for (int j = 0; j < 2; ++j) {
    int q = tid + 256 * j;
    int row = q >> 3, u = q & 7;
    int su = u ^ (row & 7);
    bptr[j] = W + (size_t)(n0 + row) * FF + su * 8;
    bdst[j] = row * 64 + u * 8;
  }

  f32x4 acc[2][4];
#pragma unroll
  for (int m = 0; m < 2; ++m)
#pragma unroll
    for (int n = 0; n < 4; ++n) acc[m][n] = (f32x4){0.f, 0.f, 0.f, 0.f};

  for (int k0 = 0; k0 < FF; k0 += 64) {
#pragma unroll
    for (int j = 0; j < 4; ++j)
      *(ushort8v*)&sA[adst[j]] = *(const ushort8v*)(aptr[j] + k0);
#pragma unroll
    for (int j = 0; j < 2; ++j)
      *(ushort8v*)&sB[bdst[j]] = *(const ushort8v*)(bptr[j] + k0);
    __syncthreads();
#pragma unroll
    for (int kk = 0; kk < 2; ++kk) {
      short8 af[2], bf[4];
#pragma unroll
      for (int m = 0; m < 2; ++m) {
        int row = wid * 32 + m * 16 + (lane & 15);
        int u = (kk * 4 + (lane >> 4)) ^ (row & 7);
        af[m] = *(const short8*)&sA[row * 64 + u * 8];
      }
#pragma unroll
      for (int n = 0; n < 4; ++n) {
        int row = n * 16 + (lane & 15);
        int u = (kk * 4 + (lane >> 4)) ^ (row & 7);
        bf[n] = *(const short8*)&sB[row * 64 + u * 8];
      }
#pragma unroll
      for (int m = 0; m < 2; ++m)
#pragma unroll
        for (int n = 0; n < 4; ++n)
          acc[m][n] = __builtin_amdgcn_mfma_f32_16x16x32_bf16(af[m], bf[n], acc[m][n], 0, 0, 0);
    }
    __syncthreads();
  }

  // epilogue: weighted atomic scatter into out (each out element hit by exactly K=2 experts)
#pragma unroll
  for (int m = 0; m < 2; ++m) {
#pragma unroll
    for (int j = 0; j < 4; ++j) {
      int row = wid * 32 + m * 16 + (lane >> 4) * 4 + j;
      int gr = m0 + row;
      if (gr < cnt) {
        int tok = toks[e * T_TOK + gr];
        float wt = wts[e * T_TOK + gr];
#pragma unroll
        for (int n = 0; n < 4; ++n) {
          int col = n0 + n * 16 + (lane & 15);
          atomicAdd(&out[(size_t)tok * HID + col], acc[m][n][j] * wt);
        }
      }
    }
  }
}

// ---------------------------------------------------------------- launch
extern "C" void kernel_launch(void* const* d_in, const int* in_sizes, int n_in,
                              void* d_out, int out_size, void* d_ws, size_t ws_size,
                              hipStream_t stream) {
  const float* x  = (const float*)d_in[0];
  const float* gw = (const float*)d_in[1];
  const float* w1 = (const float*)d_in[2];
  const float* w2 = (const float*)d_in[3];
  float* out = (float*)d_out;

  // workspace layout (bytes):
  //   0      : counts[8 * CNT_STRIDE] int  (2 KB, 4 KB reserved)
  //   4096   : toks[8*2048] int            (64 KB)
  //   69632  : wts[8*2048] float           (64 KB)
  //   135168 : xb   bf16 x                 (4 MB)
  //   +      : w1b  bf16 w1_v1             (32 MB)
  //   +      : w2b  bf16 w2                (16 MB)
  //   +      : hidden bf16 [8*2048][1024]  (32 MB)   total ~84.1 MB
  char* ws = (char*)d_ws;
  int*   counts = (int*)ws;
  int*   toks   = (int*)(ws + 4096);
  float* wts    = (float*)(ws + 4096 + 65536);
  unsigned short* xb  = (unsigned short*)(ws + 135168);
  unsigned short* w1b = xb + (size_t)T_TOK * HID;
  unsigned short* w2b = w1b + (size_t)NE * 2 * FF * HID;
  unsigned short* hid = w2b + (size_t)NE * HID * FF;

  hipMemsetAsync(counts, 0, 4096, stream);
  hipMemsetAsync(d_out, 0, (size_t)out_size * sizeof(float), stream);

  convert_kernel<<<(T_TOK * HID / 4 + 255) / 256, 256, 0, stream>>>(x, xb, T_TOK * HID / 4);
  convert_kernel<<<(NE * 2 * FF * HID / 4 + 255) / 256, 256, 0, stream>>>(w1, w1b, NE * 2 * FF * HID / 4);
  convert_kernel<<<(NE * HID * FF / 4 + 255) / 256, 256, 0, stream>>>(w2, w2b, NE * HID * FF / 4);

  router_kernel<<<T_TOK / RTOK, 256, 0, stream>>>(x, gw, counts, toks, wts);

  gemm1_kernel<<<dim3(FF / 64, T_TOK / 128, NE), 256, 0, stream>>>(xb, w1b, counts, toks, hid);
  gemm2_kernel<<<dim3(HID / 64, T_TOK / 128, NE), 256, 0, stream>>>(hid, w2b, counts, toks, wts, out);
}

// Round 8
// 207.920 us; speedup vs baseline: 1.2584x; 1.0647x over previous
//
#include <hip/hip_runtime.h>
#include <hip/hip_bf16.h>

// Problem constants (DBRX MoE): E=8 experts, top-2, H=F=1024, T=2048 tokens.
#define T_TOK 2048
#define HID   1024
#define FF    1024
#define NE    8
#define CNT_STRIDE 64          // counts[e*CNT_STRIDE]: 256B apart -> no cacheline contention
#define RBLK 8                 // tokens per router block (256 blocks -> all CUs fed)

using short8   = __attribute__((ext_vector_type(8))) short;
using f32x4    = __attribute__((ext_vector_type(4))) float;

__device__ __forceinline__ unsigned short f32_to_bf16(float f) {
  union { float f; unsigned int u; } v; v.f = f;
  unsigned int r = v.u + 0x7fffu + ((v.u >> 16) & 1u);
  return (unsigned short)(r >> 16);
}

// async global->LDS 16B: linear LDS dest (wave-uniform base + lane*16),
// per-lane global source (may be gathered / pre-swizzled).
__device__ __forceinline__ void gload_lds16(const unsigned short* g, unsigned short* l) {
  __builtin_amdgcn_global_load_lds(
      (const __attribute__((address_space(1))) void*)g,
      (__attribute__((address_space(3))) void*)l, 16, 0, 0);
}

// ---------------------------------------------------------------- convert (w1 + w2 in one launch)
__global__ __launch_bounds__(256) void convertw_kernel(const float* __restrict__ s1,
                                                       const float* __restrict__ s2,
                                                       unsigned short* __restrict__ d1,
                                                       unsigned short* __restrict__ d2,
                                                       int n1_4, int ntot_4) {
  int i = blockIdx.x * 256 + threadIdx.x;
  if (i >= ntot_4) return;
  const float* s; unsigned short* d; int k;
  if (i < n1_4) { s = s1; d = d1; k = i; }
  else          { s = s2; d = d2; k = i - n1_4; }
  const float4 v = ((const float4*)s)[k];
  ushort4 o;
  o.x = f32_to_bf16(v.x); o.y = f32_to_bf16(v.y);
  o.z = f32_to_bf16(v.z); o.w = f32_to_bf16(v.w);
  ((ushort4*)d)[k] = o;
}

// ---------------------------------------------------------------- router (+ fused x->bf16)
// 256 blocks x 8 tokens; wave handles 2 tokens (lean regs: no spill, ~16
// float4 in flight/lane). fp32 logits (exact ordering for top-2), softmax
// probs as weights (DBRX: no renorm). Writes xb (bf16 x) from the regs it
// already loaded. Block-aggregated lists: ONE atomicAdd per expert per block.
__global__ __launch_bounds__(256) void router_kernel(const float* __restrict__ x,
                                                     const float* __restrict__ gw,
                                                     int* __restrict__ counts,
                                                     int* __restrict__ toks,
                                                     float* __restrict__ wts,
                                                     unsigned short* __restrict__ xb) {
  __shared__ float gws[NE * HID];      // 32 KB
  __shared__ int   s_e[RBLK * 2];
  __shared__ float s_w[RBLK * 2];
  int tid = threadIdx.x;
  int lane = tid & 63, wid = tid >> 6;
  int t0 = blockIdx.x * RBLK;

  // 1) issue gw loads (8 float4 / thread)
  float4 greg[8];
#pragma unroll
  for (int j = 0; j < 8; ++j) greg[j] = ((const float4*)gw)[j * 256 + tid];

  // 2) issue x loads (2 tokens / wave, 4 float4 each) — in flight together
  float4 xv[2][4];
#pragma unroll
  for (int tk = 0; tk < 2; ++tk) {
    const float4* xr4 = (const float4*)(x + (size_t)(t0 + wid * 2 + tk) * HID);
#pragma unroll
    for (int c = 0; c < 4; ++c) xv[tk][c] = xr4[c * 64 + lane];
  }

  // 3) stage gw to LDS
#pragma unroll
  for (int j = 0; j < 8; ++j) ((float4*)&gws[0])[j * 256 + tid] = greg[j];
  __syncthreads();

  // 4) fused x -> bf16 (reuses xv regs; coalesced ushort4 stores)
#pragma unroll
  for (int tk = 0; tk < 2; ++tk) {
    unsigned short* xrow = xb + (size_t)(t0 + wid * 2 + tk) * HID;
#pragma unroll
    for (int c = 0; c < 4; ++c) {
      ushort4 o;
      o.x = f32_to_bf16(xv[tk][c].x); o.y = f32_to_bf16(xv[tk][c].y);
      o.z = f32_to_bf16(xv[tk][c].z); o.w = f32_to_bf16(xv[tk][c].w);
      *(ushort4*)&xrow[(c * 64 + lane) * 4] = o;
    }
  }

  // 5) dot products: gw chunk shared across the wave's 2 tokens
  float acc[2][NE];
#pragma unroll
  for (int tk = 0; tk < 2; ++tk)
#pragma unroll
    for (int e = 0; e < NE; ++e) acc[tk][e] = 0.f;

#pragma unroll
  for (int c = 0; c < 4; ++c) {
#pragma unroll
    for (int e = 0; e < NE; ++e) {
      const float4 gv = *(const float4*)&gws[e * HID + (c * 64 + lane) * 4];
#pragma unroll
      for (int tk = 0; tk < 2; ++tk) {
        acc[tk][e] = fmaf(xv[tk][c].x, gv.x, acc[tk][e]);
        acc[tk][e] = fmaf(xv[tk][c].y, gv.y, acc[tk][e]);
        acc[tk][e] = fmaf(xv[tk][c].z, gv.z, acc[tk][e]);
        acc[tk][e] = fmaf(xv[tk][c].w, gv.w, acc[tk][e]);
      }
    }
  }

  // 6) wave reduce + per-token softmax/top-2
#pragma unroll
  for (int tk = 0; tk < 2; ++tk) {
#pragma unroll
    for (int off = 32; off >= 1; off >>= 1) {
#pragma unroll
      for (int e = 0; e < NE; ++e) acc[tk][e] += __shfl_xor(acc[tk][e], off);
    }
    if (lane == 0) {
      int local = wid * 2 + tk;
      float m = acc[tk][0];
#pragma unroll
      for (int e = 1; e < NE; ++e) m = fmaxf(m, acc[tk][e]);
      float p[NE], s = 0.f;
#pragma unroll
      for (int e = 0; e < NE; ++e) { p[e] = __expf(acc[tk][e] - m); s += p[e]; }
      float inv = 1.f / s;

      int e1 = 0; float b1 = p[0];
#pragma unroll
      for (int e = 1; e < NE; ++e) if (p[e] > b1) { b1 = p[e]; e1 = e; }
      int e2 = -1; float b2 = -1.f;
#pragma unroll
      for (int e = 0; e < NE; ++e) if (e != e1 && p[e] > b2) { b2 = p[e]; e2 = e; }

      s_e[local * 2]     = e1;  s_w[local * 2]     = b1 * inv;
      s_e[local * 2 + 1] = e2;  s_w[local * 2 + 1] = b2 * inv;
    }
  }
  __syncthreads();

  // 7) 8 threads, one per expert: count -> one atomicAdd -> direct global writes
  if (tid < NE) {
    int c = 0;
#pragma unroll
    for (int i = 0; i < RBLK * 2; ++i) c += (s_e[i] == tid);
    if (c > 0) {
      int base = atomicAdd(&counts[tid * CNT_STRIDE], c);
      int p = 0;
      for (int i = 0; i < RBLK * 2; ++i) {
        if (s_e[i] == tid) {
          toks[tid * T_TOK + base + p] = t0 + (i >> 1);
          wts[tid * T_TOK + base + p] = s_w[i];
          ++p;
        }
      }
    }
  }
}

// ---------------------------------------------------------------- GEMM1
// Per expert: rows = gathered tokens, computes g (= X W1^T) and v (= X V1^T)
// for one 64-col tile each, fuses hidden = silu(g)*v, writes bf16 hidden.
// Tile: BM=128, BN=64 (per side), BK=64. 256 threads = 4 waves, wave owns 32 rows.
// Staging via global_load_lds (async DMA, no VGPR round-trip): LDS dest is
// LINEAR in thread id (byte = q*16), bank-swizzle achieved by pre-swizzling
// the per-lane GLOBAL source (rule: linear dest + inverse-swz source + swz read).
__global__ __launch_bounds__(256) void gemm1_kernel(const unsigned short* __restrict__ xb,
                                                    const unsigned short* __restrict__ w1b,
                                                    const int* __restrict__ counts,
                                                    const int* __restrict__ toks,
                                                    unsigned short* __restrict__ hidden) {
  int e = blockIdx.z;
  int cnt = counts[e * CNT_STRIDE];
  int m0 = blockIdx.y * 128;
  if (m0 >= cnt) return;
  int n0 = blockIdx.x * 64;
  const unsigned short* W = w1b + (size_t)e * (2 * FF * HID);

  __shared__ unsigned short sA[128 * 64];   // 16 KB
  __shared__ unsigned short sBg[64 * 64];   // 8 KB
  __shared__ unsigned short sBv[64 * 64];   // 8 KB

  int tid = threadIdx.x;
  int lane = tid & 63, wid = tid >> 6;

  const unsigned short* aptr[4]; int adst[4];
#pragma unroll
  for (int j = 0; j < 4; ++j) {
    int q = tid + 256 * j;            // 0..1023 : 128 rows x 8 units
    int row = q >> 3, u = q & 7;
    int gr = m0 + row;
    int tok = (gr < cnt) ? toks[e * T_TOK + gr] : 0;
    int su = u ^ (row & 7);           // pre-swizzled source unit
    aptr[j] = xb + (size_t)tok * HID + su * 8;
    adst[j] = q * 8;                  // linear LDS dest (elements)
  }
  const unsigned short* bgptr[2]; const unsigned short* bvptr[2]; int bdst[2];
#pragma unroll
  for (int j = 0; j < 2; ++j) {
    int q = tid + 256 * j;            // 0..511 : 64 rows x 8 units
    int row = q >> 3, u = q & 7;
    int su = u ^ (row & 7);
    bgptr[j] = W + (size_t)(n0 + row) * HID + su * 8;
    bvptr[j] = W + (size_t)(FF + n0 + row) * HID + su * 8;
    bdst[j] = q * 8;
  }

  f32x4 accg[2][4], accv[2][4];
#pragma unroll
  for (int m = 0; m < 2; ++m)
#pragma unroll
    for (int n = 0; n < 4; ++n) {
      accg[m][n] = (f32x4){0.f, 0.f, 0.f, 0.f};
      accv[m][n] = (f32x4){0.f, 0.f, 0.f, 0.f};
    }

  for (int k0 = 0; k0 < HID; k0 += 64) {
#pragma unroll
    for (int j = 0; j < 4; ++j) gload_lds16(aptr[j] + k0, &sA[adst[j]]);
#pragma unroll
    for (int j = 0; j < 2; ++j) {
      gload_lds16(bgptr[j] + k0, &sBg[bdst[j]]);
      gload_lds16(bvptr[j] + k0, &sBv[bdst[j]]);
    }
    __syncthreads();
#pragma unroll
    for (int kk = 0; kk < 2; ++kk) {
      short8 af[2], bgf[4], bvf[4];
#pragma unroll
      for (int m = 0; m < 2; ++m) {
        int row = wid * 32 + m * 16 + (lane & 15);
        int u = (kk * 4 + (lane >> 4)) ^ (row & 7);
        af[m] = *(const short8*)&sA[row * 64 + u * 8];
      }
#pragma unroll
      for (int n = 0; n < 4; ++n) {
        int row = n * 16 + (lane & 15);
        int u = (kk * 4 + (lane >> 4)) ^ (row & 7);
        bgf[n] = *(const short8*)&sBg[row * 64 + u * 8];
        bvf[n] = *(const short8*)&sBv[row * 64 + u * 8];
      }
#pragma unroll
      for (int m = 0; m < 2; ++m)
#pragma unroll
        for (int n = 0; n < 4; ++n) {
          accg[m][n] = __builtin_amdgcn_mfma_f32_16x16x32_bf16(af[m], bgf[n], accg[m][n], 0, 0, 0);
          accv[m][n] = __builtin_amdgcn_mfma_f32_16x16x32_bf16(af[m], bvf[n], accv[m][n], 0, 0, 0);
        }
    }
    __syncthreads();
  }

  // epilogue: hidden = silu(g) * v, bf16 store. C/D layout: col=lane&15, row=(lane>>4)*4+j
  unsigned short* Hseg = hidden + (size_t)e * T_TOK * FF;
#pragma unroll
  for (int m = 0; m < 2; ++m) {
#pragma unroll
    for (int j = 0; j < 4; ++j) {
      int row = wid * 32 + m * 16 + (lane >> 4) * 4 + j;
      int gr = m0 + row;
      if (gr < cnt) {
#pragma unroll
        for (int n = 0; n < 4; ++n) {
          int col = n0 + n * 16 + (lane & 15);
          float g = accg[m][n][j];
          float v = accv[m][n][j];
          float val = (g / (1.f + __expf(-g))) * v;
          Hseg[(size_t)gr * FF + col] = f32_to_bf16(val);
        }
      }
    }
  }
}

// ---------------------------------------------------------------- GEMM2
// out[tok,:] += wt * (hidden_row @ w2_e^T). Same tile structure, one side.
__global__ __launch_bounds__(256) void gemm2_kernel(const unsigned short* __restrict__ hidden,
                                                    const unsigned short* __restrict__ w2b,
                                                    const int* __restrict__ counts,
                                                    const int* __restrict__ toks,
                                                    const float* __restrict__ wts,
                                                    float* __restrict__ out) {
  int e = blockIdx.z;
  int cnt = counts[e * CNT_STRIDE];
  int m0 = blockIdx.y * 128;
  if (m0 >= cnt) return;
  int n0 = blockIdx.x * 64;
  const unsigned short* A = hidden + (size_t)e * T_TOK * FF;
  const unsigned short* W = w2b + (size_t)e * HID * FF;

  __shared__ unsigned short sA[128 * 64];
  __shared__ unsigned short sB[64 * 64];

  int tid = threadIdx.x;
  int lane = tid & 63, wid = tid >> 6;

  const unsigned short* aptr[4]; int adst[4];
#pragma unroll
  for (int j = 0; j < 4; ++j) {
    int q = tid + 256 * j;
    int row = q >> 3, u = q & 7;
    int su = u ^ (row & 7);
    aptr[j] = A + (size_t)(m0 + row) * FF + su * 8;   // padded rows read stale: masked at write
    adst[j] = q * 8;
  }
  const unsigned short* bptr[2]; int bdst[2];
#pragma unroll
  for (int j = 0; j < 2; ++j) {
    int q = tid + 256 * j;
    int row = q >> 3, u = q & 7;
    int su = u ^ (row & 7);
    bptr[j] = W + (size_t)(n0 + row) * FF + su * 8;
    bdst[j] = q * 8;
  }

  f32x4 acc[2][4];
#pragma unroll
  for (int m = 0; m < 2; ++m)
#pragma unroll
    for (int n = 0; n < 4; ++n) acc[m][n] = (f32x4){0.f, 0.f, 0.f, 0.f};

  for (int k0 = 0; k0 < FF; k0 += 64) {
#pragma unroll
    for (int j = 0; j < 4; ++j) gload_lds16(aptr[j] + k0, &sA[adst[j]]);
#pragma unroll
    for (int j = 0; j < 2; ++j) gload_lds16(bptr[j] + k0, &sB[bdst[j]]);
    __syncthreads();
#pragma unroll
    for (int kk = 0; kk < 2; ++kk) {
      short8 af[2], bf[4];
#pragma unroll
      for (int m = 0; m < 2; ++m) {
        int row = wid * 32 + m * 16 + (lane & 15);
        int u = (kk * 4 + (lane >> 4)) ^ (row & 7);
        af[m] = *(const short8*)&sA[row * 64 + u * 8];
      }
#pragma unroll
      for (int n = 0; n < 4; ++n) {
        int row = n * 16 + (lane & 15);
        int u = (kk * 4 + (lane >> 4)) ^ (row & 7);
        bf[n] = *(const short8*)&sB[row * 64 + u * 8];
      }
#pragma unroll
      for (int m = 0; m < 2; ++m)
#pragma unroll
        for (int n = 0; n < 4; ++n)
          acc[m][n] = __builtin_amdgcn_mfma_f32_16x16x32_bf16(af[m], bf[n], acc[m][n], 0, 0, 0);
    }
    __syncthreads();
  }

  // epilogue: weighted atomic scatter into out (each out element hit by exactly K=2 experts)
#pragma unroll
  for (int m = 0; m < 2; ++m) {
#pragma unroll
    for (int j = 0; j < 4; ++j) {
      int row = wid * 32 + m * 16 + (lane >> 4) * 4 + j;
      int gr = m0 + row;
      if (gr < cnt) {
        int tok = toks[e * T_TOK + gr];
        float wt = wts[e * T_TOK + gr];
#pragma unroll
        for (int n = 0; n < 4; ++n) {
          int col = n0 + n * 16 + (lane & 15);
          atomicAdd(&out[(size_t)tok * HID + col], acc[m][n][j] * wt);
        }
      }
    }
  }
}

// ---------------------------------------------------------------- launch
extern "C" void kernel_launch(void* const* d_in, const int* in_sizes, int n_in,
                              void* d_out, int out_size, void* d_ws, size_t ws_size,
                              hipStream_t stream) {
  const float* x  = (const float*)d_in[0];
  const float* gw = (const float*)d_in[1];
  const float* w1 = (const float*)d_in[2];
  const float* w2 = (const float*)d_in[3];
  float* out = (float*)d_out;

  // workspace layout (bytes):
  //   0      : counts[8 * CNT_STRIDE] int  (2 KB, 4 KB reserved)
  //   4096   : toks[8*2048] int            (64 KB)
  //   69632  : wts[8*2048] float           (64 KB)
  //   135168 : xb   bf16 x                 (4 MB)
  //   +      : w1b  bf16 w1_v1             (32 MB)
  //   +      : w2b  bf16 w2                (16 MB)
  //   +      : hidden bf16 [8*2048][1024]  (32 MB)   total ~84.1 MB
  char* ws = (char*)d_ws;
  int*   counts = (int*)ws;
  int*   toks   = (int*)(ws + 4096);
  float* wts    = (float*)(ws + 4096 + 65536);
  unsigned short* xb  = (unsigned short*)(ws + 135168);
  unsigned short* w1b = xb + (size_t)T_TOK * HID;
  unsigned short* w2b = w1b + (size_t)NE * 2 * FF * HID;
  unsigned short* hid = w2b + (size_t)NE * HID * FF;

  hipMemsetAsync(counts, 0, 4096, stream);
  hipMemsetAsync(d_out, 0, (size_t)out_size * sizeof(float), stream);

  router_kernel<<<T_TOK / RBLK, 256, 0, stream>>>(x, gw, counts, toks, wts, xb);

  const int n1_4 = NE * 2 * FF * HID / 4;               // w1_v1 float4 count
  const int ntot_4 = n1_4 + NE * HID * FF / 4;          // + w2
  convertw_kernel<<<(ntot_4 + 255) / 256, 256, 0, stream>>>(w1, w2, w1b, w2b, n1_4, ntot_4);

  gemm1_kernel<<<dim3(FF / 64, T_TOK / 128, NE), 256, 0, stream>>>(xb, w1b, counts, toks, hid);
  gemm2_kernel<<<dim3(HID / 64, T_TOK / 128, NE), 256, 0, stream>>>(hid, w2b, counts, toks, wts, out);
}